// Round 3
// baseline (195.063 us; speedup 1.0000x reference)
//
#include <hip/hip_runtime.h>

#define B 8
#define F 2048
#define L 1024
#define BN_EPS 1e-5f
#define THRESH 0.81f

// Native vector type accepted by __builtin_nontemporal_{load,store}
typedef float nt4 __attribute__((ext_vector_type(4)));

// ---------------------------------------------------------------------------
// Kernel A (fused pool + BN): block = one channel f, all B batches.
//   h[b,f] = BN_f( mean_L( prelu(x[b,f,:], w1) ) )
// 4 waves/block; wave w reduces rows b = w and b = w+4 (16B nontemporal loads).
// BN over the 8 pooled values is block-local (LDS), written by thread 0.
// 2048 blocks -> 8 blocks/CU -> 32 waves/CU (max occupancy).
// ---------------------------------------------------------------------------
__global__ __launch_bounds__(256) void poolbn_kernel(const float* __restrict__ x,
                                                     const float* __restrict__ p1,
                                                     const float* __restrict__ bnw,
                                                     const float* __restrict__ bnb,
                                                     float* __restrict__ h) {
    __shared__ float hh[B];
    const int f    = blockIdx.x;                      // channel
    const int wave = threadIdx.x >> 6;
    const int lane = threadIdx.x & 63;
    const float w  = p1[0];
#pragma unroll
    for (int b = wave; b < B; b += 4) {
        const nt4* xr = (const nt4*)(x + ((size_t)b * F + f) * L);
        float sum = 0.f;
#pragma unroll
        for (int k = 0; k < 4; ++k) {
            nt4 v = __builtin_nontemporal_load(&xr[lane + 64 * k]);
            sum += (v.x >= 0.f) ? v.x : w * v.x;
            sum += (v.y >= 0.f) ? v.y : w * v.y;
            sum += (v.z >= 0.f) ? v.z : w * v.z;
            sum += (v.w >= 0.f) ? v.w : w * v.w;
        }
#pragma unroll
        for (int off = 32; off > 0; off >>= 1)
            sum += __shfl_down(sum, off, 64);
        if (lane == 0) hh[b] = sum * (1.0f / L);
    }
    __syncthreads();
    if (threadIdx.x == 0) {
        float mu = 0.f;
#pragma unroll
        for (int b = 0; b < B; ++b) mu += hh[b];
        mu *= (1.0f / B);
        float var = 0.f;
#pragma unroll
        for (int b = 0; b < B; ++b) { float d = hh[b] - mu; var += d * d; }
        var *= (1.0f / B);
        const float scale = (1.0f / sqrtf(var + BN_EPS)) * bnw[f];
        const float bias  = bnb[f];
#pragma unroll
        for (int b = 0; b < B; ++b) h[b * F + f] = (hh[b] - mu) * scale + bias;
    }
}

// ---------------------------------------------------------------------------
// Kernel B: deg[b,n] = 1 + #{m : hn[b,n]*hn[b,m] > THRESH};  dinv = deg^-1/2.
// Block = 64 n's of one batch; hn[b,:] (8 KB) in LDS; broadcast reads.
// ---------------------------------------------------------------------------
__global__ __launch_bounds__(256) void deg_kernel(const float* __restrict__ hn,
                                                  float* __restrict__ dinv) {
    __shared__ float sh[F];
    __shared__ int partial[4][64];
    const int b    = blockIdx.x / (F / 64);
    const int nblk = blockIdx.x % (F / 64);
    for (int i = threadIdx.x; i < F; i += 256) sh[i] = hn[b * F + i];
    __syncthreads();
    const int nl = threadIdx.x & 63;
    const int q  = threadIdx.x >> 6;
    const int n  = nblk * 64 + nl;
    const float hv = sh[n];
    int cnt = 0;
    const int m0 = q * (F / 4);
    for (int m = 0; m < F / 4; m += 4) {
        float4 hm = *(const float4*)&sh[m0 + m];
        cnt += (hv * hm.x > THRESH);
        cnt += (hv * hm.y > THRESH);
        cnt += (hv * hm.z > THRESH);
        cnt += (hv * hm.w > THRESH);
    }
    partial[q][nl] = cnt;
    __syncthreads();
    if (q == 0) {
        int deg = 1 + partial[0][nl] + partial[1][nl] + partial[2][nl] + partial[3][nl];
        dinv[b * F + n] = 1.0f / sqrtf((float)deg);
    }
}

// ---------------------------------------------------------------------------
// Kernel C: out[b,n,m] = prelu2( dn * A[n,m] * dm ),  A = (sim>T) + I.
// Block = ROWS(8) consecutive rows of one batch: load hm/dm once per column
// chunk, reuse across 8 rows; nontemporal 16B stores (output never re-read).
// 2048 blocks -> 8/CU -> 32 waves/CU.
// ---------------------------------------------------------------------------
#define ROWS 8
__global__ __launch_bounds__(256) void out_kernel(const float* __restrict__ hn,
                                                  const float* __restrict__ dinv,
                                                  const float* __restrict__ p2,
                                                  float* __restrict__ out) {
    const int g  = blockIdx.x;                        // [0, B*F/ROWS)
    const int b  = g / (F / ROWS);
    const int n0 = (g % (F / ROWS)) * ROWS;
    const float w2 = p2[0];
    const float* hrow = hn + b * F;                   // uniform -> s_load
    const float* drow = dinv + b * F;
    float hv[ROWS], dn[ROWS];
#pragma unroll
    for (int r = 0; r < ROWS; ++r) { hv[r] = hrow[n0 + r]; dn[r] = drow[n0 + r]; }
    const float4* hm4 = (const float4*)hrow;
    const float4* dm4 = (const float4*)drow;
#pragma unroll
    for (int t = threadIdx.x; t < F / 4; t += 256) {  // 2 iterations
        float4 hm = hm4[t];
        float4 dm = dm4[t];
        const int m = t * 4;
#pragma unroll
        for (int r = 0; r < ROWS; ++r) {
            const int n = n0 + r;
            nt4 rr;
            {
                float a = (hv[r] * hm.x > THRESH) ? 1.f : 0.f; if (n == m + 0) a += 1.f;
                float v = (dn[r] * a) * dm.x; rr.x = (v >= 0.f) ? v : w2 * v;
            }
            {
                float a = (hv[r] * hm.y > THRESH) ? 1.f : 0.f; if (n == m + 1) a += 1.f;
                float v = (dn[r] * a) * dm.y; rr.y = (v >= 0.f) ? v : w2 * v;
            }
            {
                float a = (hv[r] * hm.z > THRESH) ? 1.f : 0.f; if (n == m + 2) a += 1.f;
                float v = (dn[r] * a) * dm.z; rr.z = (v >= 0.f) ? v : w2 * v;
            }
            {
                float a = (hv[r] * hm.w > THRESH) ? 1.f : 0.f; if (n == m + 3) a += 1.f;
                float v = (dn[r] * a) * dm.w; rr.w = (v >= 0.f) ? v : w2 * v;
            }
            __builtin_nontemporal_store(rr, (nt4*)(out + (size_t)(b * F + n) * F) + t);
        }
    }
}

extern "C" void kernel_launch(void* const* d_in, const int* in_sizes, int n_in,
                              void* d_out, int out_size, void* d_ws, size_t ws_size,
                              hipStream_t stream) {
    const float* x   = (const float*)d_in[0];
    const float* p1  = (const float*)d_in[1];
    const float* p2  = (const float*)d_in[2];
    const float* bnw = (const float*)d_in[3];
    const float* bnb = (const float*)d_in[4];
    float* out = (float*)d_out;

    float* h    = (float*)d_ws;            // B*F floats (pooled + BN'd)
    float* dinv = h + B * F;               // B*F floats

    poolbn_kernel<<<F, 256, 0, stream>>>(x, p1, bnw, bnb, h);
    deg_kernel<<<B * (F / 64), 256, 0, stream>>>(h, dinv);
    out_kernel<<<(B * F) / ROWS, 256, 0, stream>>>(h, dinv, p2, out);
}